// Round 5
// baseline (219.657 us; speedup 1.0000x reference)
//
#include <hip/hip_runtime.h>
#include <math.h>

#define BB 4
#define CC 1024
#define TT 1024
#define HH 16
#define HDD 64

typedef float floatx4 __attribute__((ext_vector_type(4)));
typedef __bf16 bf16x8 __attribute__((ext_vector_type(8)));
typedef __bf16 bf16x4 __attribute__((ext_vector_type(4)));

__device__ __forceinline__ void gld_lds16(const __bf16* g, __bf16* l) {
    __builtin_amdgcn_global_load_lds(
        (__attribute__((address_space(1))) void*)(g),
        (__attribute__((address_space(3))) void*)(l), 16, 0, 0);
}

// ---------------------------------------------------------------------------
// Fused prep: z<8 -> transpose (b,C,T) f32 -> (b,T,C) bf16 for x,c;
//             z==8 -> weight f32->bf16 conversion (4 matrices).
// ---------------------------------------------------------------------------
__global__ __launch_bounds__(256) void prep_kernel(
    const float* __restrict__ x, const float* __restrict__ c,
    __bf16* __restrict__ xT, __bf16* __restrict__ cT,
    const float* __restrict__ Wq, const float* __restrict__ Wk,
    const float* __restrict__ Wv, const float* __restrict__ Wo,
    __bf16* __restrict__ Wqb, __bf16* __restrict__ Wkb,
    __bf16* __restrict__ Wvb, __bf16* __restrict__ Wob) {
    __shared__ float tile[64][65];
    int tid = threadIdx.x;
    int z = blockIdx.z;
    if (z == 8) {
        // weights: 65536 threads x 64 floats
        const float* srcs[4] = {Wq, Wk, Wv, Wo};
        __bf16* dsts[4] = {Wqb, Wkb, Wvb, Wob};
        int gid = (blockIdx.y * 16 + blockIdx.x) * 256 + tid;
        int base = gid * 64;
        int mi = base >> 20;
        const float* s = srcs[mi];
        __bf16* d = dsts[mi];
        int off = base & 0xFFFFF;
#pragma unroll
        for (int u = 0; u < 16; ++u) {
            float4 v4 = *(const float4*)(s + off + u * 4);
            bf16x4 o;
            o[0] = (__bf16)v4.x; o[1] = (__bf16)v4.y;
            o[2] = (__bf16)v4.z; o[3] = (__bf16)v4.w;
            *(bf16x4*)(d + off + u * 4) = o;
        }
        return;
    }
    const float* src = (z < 4) ? x : c;
    __bf16* dst = (z < 4) ? xT : cT;
    int b = z & 3;
    int t0 = blockIdx.x * 64, c0 = blockIdx.y * 64;
    int r = tid >> 2, s16 = (tid & 3) * 16;
    const float* sp = src + (size_t)b * CC * TT + (size_t)(c0 + r) * TT + t0 + s16;
    float4 a0 = *(const float4*)(sp + 0);
    float4 a1 = *(const float4*)(sp + 4);
    float4 a2 = *(const float4*)(sp + 8);
    float4 a3 = *(const float4*)(sp + 12);
    float* tr = &tile[r][s16];
    tr[0] = a0.x; tr[1] = a0.y; tr[2]  = a0.z; tr[3]  = a0.w;
    tr[4] = a1.x; tr[5] = a1.y; tr[6]  = a1.z; tr[7]  = a1.w;
    tr[8] = a2.x; tr[9] = a2.y; tr[10] = a2.z; tr[11] = a2.w;
    tr[12] = a3.x; tr[13] = a3.y; tr[14] = a3.z; tr[15] = a3.w;
    __syncthreads();
    bf16x8 p0, p1;
#pragma unroll
    for (int j = 0; j < 8; ++j) {
        p0[j] = (__bf16)tile[s16 + j][r];
        p1[j] = (__bf16)tile[s16 + 8 + j][r];
    }
    __bf16* dp = dst + (size_t)b * TT * CC + (size_t)(t0 + r) * CC + c0 + s16;
    *(bf16x8*)(dp) = p0;
    *(bf16x8*)(dp + 8) = p1;
}

// ---------------------------------------------------------------------------
// 128x128 tile, BK=64 bf16 MFMA GEMM, B^T input (M=N=K=1024).
// EPI 0: out bf16 (b,C,T) row-major [m][n] + bias
// EPI 1: rope epilogue -> out (h,t,d) per batch base (q/k), scale qs
// EPI 2: out float (b,C,T) + bias
// ---------------------------------------------------------------------------
template <int EPI, typename OutT>
__device__ __forceinline__ void gemm_bt64(
    const __bf16* __restrict__ A, const __bf16* __restrict__ Bt,
    const float* __restrict__ bias, OutT* __restrict__ out, float qs) {
    __shared__ __bf16 smem[18432];  // 36 KB: Al [128][64], Bl [128][64], reused as o_lds
    __bf16* Al = smem;
    __bf16* Bl = smem + 8192;
    const int tid = threadIdx.x, l = tid & 63, w = tid >> 6;
    const int m0 = blockIdx.y * 128, n0 = blockIdx.x * 128;
    const int wm = (w >> 1) * 64, wn = (w & 1) * 64;
    const int lm = l & 15, lq = l >> 4;
    const int s7 = lm & 7;
    const int cg0 = (lq ^ s7) * 8, cg1 = ((4 + lq) ^ s7) * 8;
    const int srow = l >> 3, scg = l & 7;
    const int gcg = (scg ^ srow) * 8;

    // wave w stages rows w*32 .. w*32+31 (4 chunks of 8 rows) of both tiles
    const __bf16* ga = A + (size_t)(m0 + w * 32 + srow) * 1024 + gcg;
    const __bf16* gb = Bt + (size_t)(n0 + w * 32 + srow) * 1024 + gcg;
    __bf16* adst = Al + w * 32 * 64;
    __bf16* bdst = Bl + w * 32 * 64;

    floatx4 acc[4][4];
#pragma unroll
    for (int i = 0; i < 4; ++i)
#pragma unroll
        for (int j = 0; j < 4; ++j) acc[i][j] = (floatx4){0.f, 0.f, 0.f, 0.f};

#pragma unroll 1
    for (int kt = 0; kt < 16; ++kt) {
        __syncthreads();
#pragma unroll
        for (int c2 = 0; c2 < 4; ++c2) {
            gld_lds16(ga + (size_t)c2 * 8 * 1024, adst + c2 * 512);
            gld_lds16(gb + (size_t)c2 * 8 * 1024, bdst + c2 * 512);
        }
        ga += 64;
        gb += 64;
        __syncthreads();
#pragma unroll
        for (int kk = 0; kk < 2; ++kk) {
            const int cg = kk ? cg1 : cg0;
            bf16x8 af[4], bfr[4];
#pragma unroll
            for (int i = 0; i < 4; ++i) af[i] = *(bf16x8*)&Al[(wm + i * 16 + lm) * 64 + cg];
#pragma unroll
            for (int j = 0; j < 4; ++j) bfr[j] = *(bf16x8*)&Bl[(wn + j * 16 + lm) * 64 + cg];
#pragma unroll
            for (int i = 0; i < 4; ++i)
#pragma unroll
                for (int j = 0; j < 4; ++j)
                    acc[i][j] = __builtin_amdgcn_mfma_f32_16x16x32_bf16(af[i], bfr[j], acc[i][j], 0, 0, 0);
        }
    }

    if (EPI == 1) {
        // ---- bias + RoPE in registers, write (h,t,d) via LDS bounce ----
        float b4[4][4];
#pragma unroll
        for (int i = 0; i < 4; ++i)
#pragma unroll
            for (int r = 0; r < 4; ++r) b4[i][r] = bias[m0 + wm + i * 16 + lq * 4 + r];
#pragma unroll
        for (int r = 0; r < 4; ++r) {
            // theta = 10000^(-(lq*4+r)/16)
            float theta = __expf(-0.57564627f * (float)(lq * 4 + r));
#pragma unroll
            for (int j = 0; j < 4; ++j) {
                float ang = (float)(n0 + wn + j * 16 + lm) * theta;
                float cs = __cosf(ang), sn = __sinf(ang);
                float a0 = acc[0][j][r] + b4[0][r];
                float a1 = acc[1][j][r] + b4[1][r];
                acc[0][j][r] = (a0 * cs - a1 * sn) * qs;
                acc[1][j][r] = (a1 * cs + a0 * sn) * qs;
                acc[2][j][r] = (acc[2][j][r] + b4[2][r]) * qs;
                acc[3][j][r] = (acc[3][j][r] + b4[3][r]) * qs;
            }
        }
        __syncthreads();  // all LDS frag reads done; reuse smem as o_lds [256][72]
        const int hl = wm >> 6;
#pragma unroll
        for (int j = 0; j < 4; ++j) {
            int row = hl * 128 + wn + j * 16 + lm;
#pragma unroll
            for (int i = 0; i < 4; ++i) {
                bf16x4 pk;
#pragma unroll
                for (int r = 0; r < 4; ++r) pk[r] = (__bf16)acc[i][j][r];
                *(bf16x4*)&smem[row * 72 + i * 16 + lq * 4] = pk;
            }
        }
        __syncthreads();
        const size_t hbase = (size_t)(m0 >> 6) * (TT * 64);
#pragma unroll
        for (int it = 0; it < 8; ++it) {
            int chunk = tid + 256 * it;
            int row = chunk >> 3, off = (chunk & 7) * 8;  // row 0..255
            int hh = row >> 7, t = n0 + (row & 127);
            *(bf16x8*)&out[hbase + (size_t)hh * (TT * 64) + (size_t)t * 64 + off] =
                *(bf16x8*)&smem[row * 72 + off];
        }
    } else {
#pragma unroll
        for (int i = 0; i < 4; ++i) {
            int mbase = m0 + wm + i * 16 + lq * 4;
#pragma unroll
            for (int r = 0; r < 4; ++r) {
                float bv = bias[mbase + r];
                size_t rowoff = (size_t)(mbase + r) * 1024 + n0 + wn + lm;
#pragma unroll
                for (int j = 0; j < 4; ++j)
                    out[rowoff + j * 16] = (OutT)(acc[i][j][r] + bv);
            }
        }
    }
}

__global__ __launch_bounds__(256) void gemm_qkv_kernel(
    const __bf16* __restrict__ Wqb, const __bf16* __restrict__ Wkb, const __bf16* __restrict__ Wvb,
    const __bf16* __restrict__ xT, const __bf16* __restrict__ cT,
    const float* __restrict__ bq, const float* __restrict__ bk, const float* __restrict__ bv,
    __bf16* __restrict__ qhb, __bf16* __restrict__ khb, __bf16* __restrict__ vb) {
    int z = blockIdx.z, which = z >> 2, b = z & 3;
    if (which == 0) {
        // q: rope + softmax-scale, out (b,h,t,d)
        gemm_bt64<1, __bf16>(Wqb, xT + (size_t)b * TT * CC, bq,
                             qhb + (size_t)b * HH * TT * 64, 0.18033688f);
    } else if (which == 1) {
        // k: rope, out (b,h,t,d)
        gemm_bt64<1, __bf16>(Wkb, cT + (size_t)b * TT * CC, bk,
                             khb + (size_t)b * HH * TT * 64, 1.0f);
    } else {
        // v: plain, out (b,C,T)
        gemm_bt64<0, __bf16>(Wvb, cT + (size_t)b * TT * CC, bv,
                             vb + (size_t)b * CC * TT, 1.0f);
    }
}

__global__ __launch_bounds__(256) void gemm_out_kernel(
    const __bf16* __restrict__ Wob, const __bf16* __restrict__ attT,
    const float* __restrict__ bo, float* __restrict__ out) {
    int b = blockIdx.z;
    gemm_bt64<2, float>(Wob, attT + (size_t)b * TT * CC, bo, out + (size_t)b * CC * TT, 1.0f);
}

// ---------------------------------------------------------------------------
// Flash-style attention (v4 structure, unchanged from R4):
//  - 32 q-rows/wave, Q fragments in registers, double-buffered K/V,
//    one barrier per tile, stage-ahead.
// ---------------------------------------------------------------------------
#define ATTN_STAGE(KB, VB)                      \
    do {                                        \
        gld_lds16(kg, &KB[w * 1024]);           \
        gld_lds16(kg + 512, &KB[w * 1024 + 512]); \
        gld_lds16(vg, &VB[w * 1024]);           \
        gld_lds16(vg + 8 * TT, &VB[w * 1024 + 512]); \
        kg += 4096;                             \
        vg += 64;                               \
    } while (0)

#define ATTN_STEP(KB, VB)                                                            \
    do {                                                                             \
        floatx4 sT[2][4];                                                            \
        _Pragma("unroll") for (int i = 0; i < 4; ++i) {                              \
            sT[0][i] = (floatx4){0.f, 0.f, 0.f, 0.f};                                \
            sT[1][i] = (floatx4){0.f, 0.f, 0.f, 0.f};                                \
        }                                                                            \
        _Pragma("unroll") for (int i = 0; i < 4; ++i) {                              \
            bf16x8 kf0 = *(bf16x8*)&KB[koff + i * 1024 + cg0];                       \
            bf16x8 kf1 = *(bf16x8*)&KB[koff + i * 1024 + cg1];                       \
            sT[0][i] = __builtin_amdgcn_mfma_f32_16x16x32_bf16(kf0, qf00, sT[0][i], 0, 0, 0); \
            sT[0][i] = __builtin_amdgcn_mfma_f32_16x16x32_bf16(kf1, qf01, sT[0][i], 0, 0, 0); \
            sT[1][i] = __builtin_amdgcn_mfma_f32_16x16x32_bf16(kf0, qf10, sT[1][i], 0, 0, 0); \
            sT[1][i] = __builtin_amdgcn_mfma_f32_16x16x32_bf16(kf1, qf11, sT[1][i], 0, 0, 0); \
        }                                                                            \
        float rs0 = 0.f, rs1 = 0.f;                                                  \
        _Pragma("unroll") for (int i = 0; i < 4; ++i)                                \
            _Pragma("unroll") for (int r = 0; r < 4; ++r) {                          \
                float e0 = __builtin_amdgcn_exp2f(sT[0][i][r]);                      \
                float e1 = __builtin_amdgcn_exp2f(sT[1][i][r]);                      \
                sT[0][i][r] = e0; rs0 += e0;                                         \
                sT[1][i][r] = e1; rs1 += e1;                                         \
            }                                                                        \
        rs0 += __shfl_xor(rs0, 16, 64); rs0 += __shfl_xor(rs0, 32, 64);              \
        rs1 += __shfl_xor(rs1, 16, 64); rs1 += __shfl_xor(rs1, 32, 64);              \
        l_acc0 += rs0; l_acc1 += rs1;                                                \
        _Pragma("unroll") for (int i = 0; i < 4; ++i) {                              \
            bf16x4 p0, p1;                                                           \
            _Pragma("unroll") for (int r = 0; r < 4; ++r) {                          \
                p0[r] = (__bf16)sT[0][i][r];                                         \
                p1[r] = (__bf16)sT[1][i][r];                                         \
            }                                                                        \
            *(bf16x4*)&pwl[i * 16 + lq * 4] = p0;                                    \
            *(bf16x4*)&pwl[1152 + i * 16 + lq * 4] = p1;                             \
        }                                                                            \
        asm volatile("s_waitcnt lgkmcnt(0)" ::: "memory");                           \
        _Pragma("unroll") for (int ss = 0; ss < 2; ++ss) {                           \
            bf16x8 ap0 = *(bf16x8*)&pwl[ss * 32 + lq * 8];                           \
            bf16x8 ap1 = *(bf16x8*)&pwl[1152 + ss * 32 + lq * 8];                    \
            const int cgv = ss ? cg1 : cg0;                                          \
            _Pragma("unroll") for (int j = 0; j < 4; ++j) {                          \
                bf16x8 vf = *(bf16x8*)&VB[koff + j * 1024 + cgv];                    \
                o_acc[0][j] = __builtin_amdgcn_mfma_f32_16x16x32_bf16(ap0, vf, o_acc[0][j], 0, 0, 0); \
                o_acc[1][j] = __builtin_amdgcn_mfma_f32_16x16x32_bf16(ap1, vf, o_acc[1][j], 0, 0, 0); \
            }                                                                        \
        }                                                                            \
    } while (0)

__global__ __launch_bounds__(256, 4) void attn_kernel(
    const __bf16* __restrict__ qh, const __bf16* __restrict__ kh,
    const __bf16* __restrict__ v, __bf16* __restrict__ attT) {
    const int bh = blockIdx.x, b = bh >> 4, h = bh & 15;
    const int tq0 = blockIdx.y * 128;
    const int tid = threadIdx.x, l = tid & 63, w = tid >> 6;
    const int lm = l & 15, lq = l >> 4;

    __shared__ __bf16 k0[4096], v0[4096], k1[4096], v1[4096];
    __shared__ __bf16 p_lds[9216];  // 4 waves x [32 t][72]

    const int cg0 = (lq ^ (lm & 7)) * 8;
    const int cg1 = ((4 + lq) ^ (lm & 7)) * 8;
    const int koff = lm * 64;
    __bf16* pwl = p_lds + w * 2304 + lm * 72;

    const __bf16* qbase = qh + (size_t)bh * TT * 64 + (size_t)(tq0 + w * 32 + lm) * 64 + lq * 8;
    bf16x8 qf00 = *(const bf16x8*)(qbase);
    bf16x8 qf01 = *(const bf16x8*)(qbase + 32);
    bf16x8 qf10 = *(const bf16x8*)(qbase + 1024);
    bf16x8 qf11 = *(const bf16x8*)(qbase + 1024 + 32);

    const int srow = l >> 3, scg = l & 7;
    const int gcg = (scg ^ srow) * 8;
    const __bf16* kg = kh + (size_t)bh * TT * 64 + (size_t)(w * 16 + srow) * 64 + gcg;
    const __bf16* vg = v + (size_t)b * CC * TT + (size_t)(h * 64 + w * 16 + srow) * TT + gcg;

    floatx4 o_acc[2][4];
#pragma unroll
    for (int j = 0; j < 4; ++j) {
        o_acc[0][j] = (floatx4){0.f, 0.f, 0.f, 0.f};
        o_acc[1][j] = (floatx4){0.f, 0.f, 0.f, 0.f};
    }
    float l_acc0 = 0.f, l_acc1 = 0.f;

    ATTN_STAGE(k0, v0);
#pragma unroll 1
    for (int st = 0; st < 16; st += 2) {
        __syncthreads();
        ATTN_STAGE(k1, v1);
        ATTN_STEP(k0, v0);
        __syncthreads();
        if (st + 2 < 16) ATTN_STAGE(k0, v0);
        ATTN_STEP(k1, v1);
    }

    float inv0[4], inv1[4];
#pragma unroll
    for (int r = 0; r < 4; ++r) {
        inv0[r] = 1.0f / __shfl(l_acc0, lq * 4 + r, 64);
        inv1[r] = 1.0f / __shfl(l_acc1, lq * 4 + r, 64);
    }
#pragma unroll
    for (int j = 0; j < 4; ++j)
#pragma unroll
        for (int r = 0; r < 4; ++r) {
            p_lds[(w * 32 + lq * 4 + r) * 72 + j * 16 + lm] = (__bf16)(o_acc[0][j][r] * inv0[r]);
            p_lds[(w * 32 + 16 + lq * 4 + r) * 72 + j * 16 + lm] = (__bf16)(o_acc[1][j][r] * inv1[r]);
        }
    __syncthreads();
    __bf16* obase = attT + (size_t)b * TT * CC + (size_t)tq0 * CC + h * 64;
#pragma unroll
    for (int it = 0; it < 4; ++it) {
        int chunk = tid + 256 * it;
        int row = chunk >> 3, off = (chunk & 7) * 8;
        *(bf16x8*)&obase[(size_t)row * CC + off] = *(bf16x8*)&p_lds[row * 72 + off];
    }
}

// ---------------------------------------------------------------------------
extern "C" void kernel_launch(void* const* d_in, const int* in_sizes, int n_in,
                              void* d_out, int out_size, void* d_ws, size_t ws_size,
                              hipStream_t stream) {
    const float* x = (const float*)d_in[0];
    const float* c = (const float*)d_in[1];
    const float* Wq = (const float*)d_in[3];
    const float* bq = (const float*)d_in[4];
    const float* Wk = (const float*)d_in[5];
    const float* bk = (const float*)d_in[6];
    const float* Wv = (const float*)d_in[7];
    const float* bv = (const float*)d_in[8];
    const float* Wo = (const float*)d_in[9];
    const float* bo = (const float*)d_in[10];

    const size_t MB = 1024ull * 1024ull;
    char* ws = (char*)d_ws;
    __bf16* Wqb  = (__bf16*)(ws + 0 * MB);
    __bf16* Wkb  = (__bf16*)(ws + 2 * MB);
    __bf16* Wvb  = (__bf16*)(ws + 4 * MB);
    __bf16* Wob  = (__bf16*)(ws + 6 * MB);
    __bf16* xT   = (__bf16*)(ws + 8 * MB);
    __bf16* cT   = (__bf16*)(ws + 16 * MB);
    __bf16* qhb  = (__bf16*)(ws + 24 * MB);  // (b,h,t,d) roped+scaled
    __bf16* khb  = (__bf16*)(ws + 32 * MB);  // (b,h,t,d) roped
    __bf16* vbuf = (__bf16*)(ws + 40 * MB);  // (b,C,T)
    __bf16* attT = (__bf16*)(ws + 48 * MB);  // (b,t,c)

    prep_kernel<<<dim3(16, 16, 9), 256, 0, stream>>>(x, c, xT, cT, Wq, Wk, Wv, Wo,
                                                     Wqb, Wkb, Wvb, Wob);
    gemm_qkv_kernel<<<dim3(8, 8, 12), 256, 0, stream>>>(Wqb, Wkb, Wvb, xT, cT, bq, bk, bv,
                                                        qhb, khb, vbuf);
    attn_kernel<<<dim3(64, 8), 256, 0, stream>>>(qhb, khb, vbuf, attT);
    gemm_out_kernel<<<dim3(8, 8, 4), 256, 0, stream>>>(Wob, attT, bo, (float*)d_out);
}

// Round 6
// 214.725 us; speedup vs baseline: 1.0230x; 1.0230x over previous
//
#include <hip/hip_runtime.h>
#include <math.h>

#define BB 4
#define CC 1024
#define TT 1024
#define HH 16
#define HDD 64

typedef float floatx4 __attribute__((ext_vector_type(4)));
typedef __bf16 bf16x8 __attribute__((ext_vector_type(8)));
typedef __bf16 bf16x4 __attribute__((ext_vector_type(4)));

__device__ __forceinline__ void gld_lds16(const __bf16* g, __bf16* l) {
    __builtin_amdgcn_global_load_lds(
        (__attribute__((address_space(1))) void*)(g),
        (__attribute__((address_space(3))) void*)(l), 16, 0, 0);
}

// ---------------------------------------------------------------------------
// Fused prep: z<8 -> transpose (b,C,T) f32 -> (b,T,C) bf16 for x,c;
//             z==8 -> weight f32->bf16 conversion (coalesced: each pass
//             moves 256 threads x float4 = 4 KB contiguous).
// ---------------------------------------------------------------------------
__global__ __launch_bounds__(256) void prep_kernel(
    const float* __restrict__ x, const float* __restrict__ c,
    __bf16* __restrict__ xT, __bf16* __restrict__ cT,
    const float* __restrict__ Wq, const float* __restrict__ Wk,
    const float* __restrict__ Wv, const float* __restrict__ Wo,
    __bf16* __restrict__ Wqb, __bf16* __restrict__ Wkb,
    __bf16* __restrict__ Wvb, __bf16* __restrict__ Wob) {
    __shared__ float tile[64][65];
    int tid = threadIdx.x;
    int z = blockIdx.z;
    if (z == 8) {
        // 256 blocks, each converts 16384 consecutive floats of one matrix
        const float* srcs[4] = {Wq, Wk, Wv, Wo};
        __bf16* dsts[4] = {Wqb, Wkb, Wvb, Wob};
        int bid = blockIdx.y * 16 + blockIdx.x;   // 0..255
        int mi = bid >> 6;                        // 64 blocks per matrix
        const float* s = srcs[mi];
        __bf16* d = dsts[mi];
        int base = (bid & 63) * 16384;
#pragma unroll
        for (int u = 0; u < 16; ++u) {
            int idx = base + u * 1024 + tid * 4;
            float4 v4 = *(const float4*)(s + idx);
            bf16x4 o;
            o[0] = (__bf16)v4.x; o[1] = (__bf16)v4.y;
            o[2] = (__bf16)v4.z; o[3] = (__bf16)v4.w;
            *(bf16x4*)(d + idx) = o;
        }
        return;
    }
    const float* src = (z < 4) ? x : c;
    __bf16* dst = (z < 4) ? xT : cT;
    int b = z & 3;
    int t0 = blockIdx.x * 64, c0 = blockIdx.y * 64;
    int r = tid >> 2, s16 = (tid & 3) * 16;
    const float* sp = src + (size_t)b * CC * TT + (size_t)(c0 + r) * TT + t0 + s16;
    float4 a0 = *(const float4*)(sp + 0);
    float4 a1 = *(const float4*)(sp + 4);
    float4 a2 = *(const float4*)(sp + 8);
    float4 a3 = *(const float4*)(sp + 12);
    float* tr = &tile[r][s16];
    tr[0] = a0.x; tr[1] = a0.y; tr[2]  = a0.z; tr[3]  = a0.w;
    tr[4] = a1.x; tr[5] = a1.y; tr[6]  = a1.z; tr[7]  = a1.w;
    tr[8] = a2.x; tr[9] = a2.y; tr[10] = a2.z; tr[11] = a2.w;
    tr[12] = a3.x; tr[13] = a3.y; tr[14] = a3.z; tr[15] = a3.w;
    __syncthreads();
    bf16x8 p0, p1;
#pragma unroll
    for (int j = 0; j < 8; ++j) {
        p0[j] = (__bf16)tile[s16 + j][r];
        p1[j] = (__bf16)tile[s16 + 8 + j][r];
    }
    __bf16* dp = dst + (size_t)b * TT * CC + (size_t)(t0 + r) * CC + c0 + s16;
    *(bf16x8*)(dp) = p0;
    *(bf16x8*)(dp + 8) = p1;
}

// ---------------------------------------------------------------------------
// 128x128 tile, BK=64 bf16 MFMA GEMM, B^T input (M=N=K=1024).
// smem: caller-provided 18432-elem (36 KB) workspace — shared across all
// template instantiations in a kernel (kernel-scope __shared__).
// EPI 0: out bf16 (b,C,T) row-major [m][n] + bias
// EPI 1: rope epilogue -> out (h,t,d) per batch base (q/k), scale qs
// EPI 2: out float (b,C,T) + bias
// ---------------------------------------------------------------------------
template <int EPI, typename OutT>
__device__ __forceinline__ void gemm_bt64(
    __bf16* smem, const __bf16* __restrict__ A, const __bf16* __restrict__ Bt,
    const float* __restrict__ bias, OutT* __restrict__ out, float qs) {
    __bf16* Al = smem;
    __bf16* Bl = smem + 8192;
    const int tid = threadIdx.x, l = tid & 63, w = tid >> 6;
    const int m0 = blockIdx.y * 128, n0 = blockIdx.x * 128;
    const int wm = (w >> 1) * 64, wn = (w & 1) * 64;
    const int lm = l & 15, lq = l >> 4;
    const int s7 = lm & 7;
    const int cg0 = (lq ^ s7) * 8, cg1 = ((4 + lq) ^ s7) * 8;
    const int srow = l >> 3, scg = l & 7;
    const int gcg = (scg ^ srow) * 8;

    // wave w stages rows w*32 .. w*32+31 (4 chunks of 8 rows) of both tiles
    const __bf16* ga = A + (size_t)(m0 + w * 32 + srow) * 1024 + gcg;
    const __bf16* gb = Bt + (size_t)(n0 + w * 32 + srow) * 1024 + gcg;
    __bf16* adst = Al + w * 32 * 64;
    __bf16* bdst = Bl + w * 32 * 64;

    floatx4 acc[4][4];
#pragma unroll
    for (int i = 0; i < 4; ++i)
#pragma unroll
        for (int j = 0; j < 4; ++j) acc[i][j] = (floatx4){0.f, 0.f, 0.f, 0.f};

#pragma unroll 1
    for (int kt = 0; kt < 16; ++kt) {
        __syncthreads();
#pragma unroll
        for (int c2 = 0; c2 < 4; ++c2) {
            gld_lds16(ga + (size_t)c2 * 8 * 1024, adst + c2 * 512);
            gld_lds16(gb + (size_t)c2 * 8 * 1024, bdst + c2 * 512);
        }
        ga += 64;
        gb += 64;
        __syncthreads();
#pragma unroll
        for (int kk = 0; kk < 2; ++kk) {
            const int cg = kk ? cg1 : cg0;
            bf16x8 af[4], bfr[4];
#pragma unroll
            for (int i = 0; i < 4; ++i) af[i] = *(bf16x8*)&Al[(wm + i * 16 + lm) * 64 + cg];
#pragma unroll
            for (int j = 0; j < 4; ++j) bfr[j] = *(bf16x8*)&Bl[(wn + j * 16 + lm) * 64 + cg];
#pragma unroll
            for (int i = 0; i < 4; ++i)
#pragma unroll
                for (int j = 0; j < 4; ++j)
                    acc[i][j] = __builtin_amdgcn_mfma_f32_16x16x32_bf16(af[i], bfr[j], acc[i][j], 0, 0, 0);
        }
    }

    if (EPI == 1) {
        // ---- bias + RoPE in registers, write (h,t,d) via LDS bounce ----
        float b4[4][4];
#pragma unroll
        for (int i = 0; i < 4; ++i)
#pragma unroll
            for (int r = 0; r < 4; ++r) b4[i][r] = bias[m0 + wm + i * 16 + lq * 4 + r];
#pragma unroll
        for (int r = 0; r < 4; ++r) {
            // theta = 10000^(-(lq*4+r)/16)
            float theta = __expf(-0.57564627f * (float)(lq * 4 + r));
#pragma unroll
            for (int j = 0; j < 4; ++j) {
                float ang = (float)(n0 + wn + j * 16 + lm) * theta;
                float cs = __cosf(ang), sn = __sinf(ang);
                float a0 = acc[0][j][r] + b4[0][r];
                float a1 = acc[1][j][r] + b4[1][r];
                acc[0][j][r] = (a0 * cs - a1 * sn) * qs;
                acc[1][j][r] = (a1 * cs + a0 * sn) * qs;
                acc[2][j][r] = (acc[2][j][r] + b4[2][r]) * qs;
                acc[3][j][r] = (acc[3][j][r] + b4[3][r]) * qs;
            }
        }
        __syncthreads();  // all LDS frag reads done; reuse smem as o_lds [256][72]
        const int hl = wm >> 6;
#pragma unroll
        for (int j = 0; j < 4; ++j) {
            int row = hl * 128 + wn + j * 16 + lm;
#pragma unroll
            for (int i = 0; i < 4; ++i) {
                bf16x4 pk;
#pragma unroll
                for (int r = 0; r < 4; ++r) pk[r] = (__bf16)acc[i][j][r];
                *(bf16x4*)&smem[row * 72 + i * 16 + lq * 4] = pk;
            }
        }
        __syncthreads();
        const size_t hbase = (size_t)(m0 >> 6) * (TT * 64);
#pragma unroll
        for (int it = 0; it < 8; ++it) {
            int chunk = tid + 256 * it;
            int row = chunk >> 3, off = (chunk & 7) * 8;  // row 0..255
            int hh = row >> 7, t = n0 + (row & 127);
            *(bf16x8*)&out[hbase + (size_t)hh * (TT * 64) + (size_t)t * 64 + off] =
                *(bf16x8*)&smem[row * 72 + off];
        }
    } else {
#pragma unroll
        for (int i = 0; i < 4; ++i) {
            int mbase = m0 + wm + i * 16 + lq * 4;
#pragma unroll
            for (int r = 0; r < 4; ++r) {
                float bv = bias[mbase + r];
                size_t rowoff = (size_t)(mbase + r) * 1024 + n0 + wn + lm;
#pragma unroll
                for (int j = 0; j < 4; ++j)
                    out[rowoff + j * 16] = (OutT)(acc[i][j][r] + bv);
            }
        }
    }
}

__global__ __launch_bounds__(256) void gemm_qkv_kernel(
    const __bf16* __restrict__ Wqb, const __bf16* __restrict__ Wkb, const __bf16* __restrict__ Wvb,
    const __bf16* __restrict__ xT, const __bf16* __restrict__ cT,
    const float* __restrict__ bq, const float* __restrict__ bk, const float* __restrict__ bv,
    __bf16* __restrict__ qhb, __bf16* __restrict__ khb, __bf16* __restrict__ vb) {
    __shared__ __bf16 smem[18432];  // single 36 KB allocation for all EPI paths
    int z = blockIdx.z, which = z >> 2, b = z & 3;
    if (which == 0) {
        gemm_bt64<1, __bf16>(smem, Wqb, xT + (size_t)b * TT * CC, bq,
                             qhb + (size_t)b * HH * TT * 64, 0.18033688f);
    } else if (which == 1) {
        gemm_bt64<1, __bf16>(smem, Wkb, cT + (size_t)b * TT * CC, bk,
                             khb + (size_t)b * HH * TT * 64, 1.0f);
    } else {
        gemm_bt64<0, __bf16>(smem, Wvb, cT + (size_t)b * TT * CC, bv,
                             vb + (size_t)b * CC * TT, 1.0f);
    }
}

__global__ __launch_bounds__(256) void gemm_out_kernel(
    const __bf16* __restrict__ Wob, const __bf16* __restrict__ attT,
    const float* __restrict__ bo, float* __restrict__ out) {
    __shared__ __bf16 smem[18432];
    int b = blockIdx.z;
    gemm_bt64<2, float>(smem, Wob, attT + (size_t)b * TT * CC, bo,
                        out + (size_t)b * CC * TT, 1.0f);
}

// ---------------------------------------------------------------------------
// Flash-style attention (v4 structure):
//  - 32 q-rows/wave, Q fragments in registers, double-buffered K/V,
//    one barrier per tile, stage-ahead.
// ---------------------------------------------------------------------------
#define ATTN_STAGE(KB, VB)                      \
    do {                                        \
        gld_lds16(kg, &KB[w * 1024]);           \
        gld_lds16(kg + 512, &KB[w * 1024 + 512]); \
        gld_lds16(vg, &VB[w * 1024]);           \
        gld_lds16(vg + 8 * TT, &VB[w * 1024 + 512]); \
        kg += 4096;                             \
        vg += 64;                               \
    } while (0)

#define ATTN_STEP(KB, VB)                                                            \
    do {                                                                             \
        floatx4 sT[2][4];                                                            \
        _Pragma("unroll") for (int i = 0; i < 4; ++i) {                              \
            sT[0][i] = (floatx4){0.f, 0.f, 0.f, 0.f};                                \
            sT[1][i] = (floatx4){0.f, 0.f, 0.f, 0.f};                                \
        }                                                                            \
        _Pragma("unroll") for (int i = 0; i < 4; ++i) {                              \
            bf16x8 kf0 = *(bf16x8*)&KB[koff + i * 1024 + cg0];                       \
            bf16x8 kf1 = *(bf16x8*)&KB[koff + i * 1024 + cg1];                       \
            sT[0][i] = __builtin_amdgcn_mfma_f32_16x16x32_bf16(kf0, qf00, sT[0][i], 0, 0, 0); \
            sT[0][i] = __builtin_amdgcn_mfma_f32_16x16x32_bf16(kf1, qf01, sT[0][i], 0, 0, 0); \
            sT[1][i] = __builtin_amdgcn_mfma_f32_16x16x32_bf16(kf0, qf10, sT[1][i], 0, 0, 0); \
            sT[1][i] = __builtin_amdgcn_mfma_f32_16x16x32_bf16(kf1, qf11, sT[1][i], 0, 0, 0); \
        }                                                                            \
        float rs0 = 0.f, rs1 = 0.f;                                                  \
        _Pragma("unroll") for (int i = 0; i < 4; ++i)                                \
            _Pragma("unroll") for (int r = 0; r < 4; ++r) {                          \
                float e0 = __builtin_amdgcn_exp2f(sT[0][i][r]);                      \
                float e1 = __builtin_amdgcn_exp2f(sT[1][i][r]);                      \
                sT[0][i][r] = e0; rs0 += e0;                                         \
                sT[1][i][r] = e1; rs1 += e1;                                         \
            }                                                                        \
        rs0 += __shfl_xor(rs0, 16, 64); rs0 += __shfl_xor(rs0, 32, 64);              \
        rs1 += __shfl_xor(rs1, 16, 64); rs1 += __shfl_xor(rs1, 32, 64);              \
        l_acc0 += rs0; l_acc1 += rs1;                                                \
        _Pragma("unroll") for (int i = 0; i < 4; ++i) {                              \
            bf16x4 p0, p1;                                                           \
            _Pragma("unroll") for (int r = 0; r < 4; ++r) {                          \
                p0[r] = (__bf16)sT[0][i][r];                                         \
                p1[r] = (__bf16)sT[1][i][r];                                         \
            }                                                                        \
            *(bf16x4*)&pwl[i * 16 + lq * 4] = p0;                                    \
            *(bf16x4*)&pwl[1152 + i * 16 + lq * 4] = p1;                             \
        }                                                                            \
        asm volatile("s_waitcnt lgkmcnt(0)" ::: "memory");                           \
        _Pragma("unroll") for (int ss = 0; ss < 2; ++ss) {                           \
            bf16x8 ap0 = *(bf16x8*)&pwl[ss * 32 + lq * 8];                           \
            bf16x8 ap1 = *(bf16x8*)&pwl[1152 + ss * 32 + lq * 8];                    \
            const int cgv = ss ? cg1 : cg0;                                          \
            _Pragma("unroll") for (int j = 0; j < 4; ++j) {                          \
                bf16x8 vf = *(bf16x8*)&VB[koff + j * 1024 + cgv];                    \
                o_acc[0][j] = __builtin_amdgcn_mfma_f32_16x16x32_bf16(ap0, vf, o_acc[0][j], 0, 0, 0); \
                o_acc[1][j] = __builtin_amdgcn_mfma_f32_16x16x32_bf16(ap1, vf, o_acc[1][j], 0, 0, 0); \
            }                                                                        \
        }                                                                            \
    } while (0)

__global__ __launch_bounds__(256, 4) void attn_kernel(
    const __bf16* __restrict__ qh, const __bf16* __restrict__ kh,
    const __bf16* __restrict__ v, __bf16* __restrict__ attT) {
    const int bh = blockIdx.x, b = bh >> 4, h = bh & 15;
    const int tq0 = blockIdx.y * 128;
    const int tid = threadIdx.x, l = tid & 63, w = tid >> 6;
    const int lm = l & 15, lq = l >> 4;

    __shared__ __bf16 k0[4096], v0[4096], k1[4096], v1[4096];
    __shared__ __bf16 p_lds[9216];  // 4 waves x [32 t][72]

    const int cg0 = (lq ^ (lm & 7)) * 8;
    const int cg1 = ((4 + lq) ^ (lm & 7)) * 8;
    const int koff = lm * 64;
    __bf16* pwl = p_lds + w * 2304 + lm * 72;

    const __bf16* qbase = qh + (size_t)bh * TT * 64 + (size_t)(tq0 + w * 32 + lm) * 64 + lq * 8;
    bf16x8 qf00 = *(const bf16x8*)(qbase);
    bf16x8 qf01 = *(const bf16x8*)(qbase + 32);
    bf16x8 qf10 = *(const bf16x8*)(qbase + 1024);
    bf16x8 qf11 = *(const bf16x8*)(qbase + 1024 + 32);

    const int srow = l >> 3, scg = l & 7;
    const int gcg = (scg ^ srow) * 8;
    const __bf16* kg = kh + (size_t)bh * TT * 64 + (size_t)(w * 16 + srow) * 64 + gcg;
    const __bf16* vg = v + (size_t)b * CC * TT + (size_t)(h * 64 + w * 16 + srow) * TT + gcg;

    floatx4 o_acc[2][4];
#pragma unroll
    for (int j = 0; j < 4; ++j) {
        o_acc[0][j] = (floatx4){0.f, 0.f, 0.f, 0.f};
        o_acc[1][j] = (floatx4){0.f, 0.f, 0.f, 0.f};
    }
    float l_acc0 = 0.f, l_acc1 = 0.f;

    ATTN_STAGE(k0, v0);
#pragma unroll 1
    for (int st = 0; st < 16; st += 2) {
        __syncthreads();
        ATTN_STAGE(k1, v1);
        ATTN_STEP(k0, v0);
        __syncthreads();
        if (st + 2 < 16) ATTN_STAGE(k0, v0);
        ATTN_STEP(k1, v1);
    }

    float inv0[4], inv1[4];
#pragma unroll
    for (int r = 0; r < 4; ++r) {
        inv0[r] = 1.0f / __shfl(l_acc0, lq * 4 + r, 64);
        inv1[r] = 1.0f / __shfl(l_acc1, lq * 4 + r, 64);
    }
#pragma unroll
    for (int j = 0; j < 4; ++j)
#pragma unroll
        for (int r = 0; r < 4; ++r) {
            p_lds[(w * 32 + lq * 4 + r) * 72 + j * 16 + lm] = (__bf16)(o_acc[0][j][r] * inv0[r]);
            p_lds[(w * 32 + 16 + lq * 4 + r) * 72 + j * 16 + lm] = (__bf16)(o_acc[1][j][r] * inv1[r]);
        }
    __syncthreads();
    __bf16* obase = attT + (size_t)b * TT * CC + (size_t)tq0 * CC + h * 64;
#pragma unroll
    for (int it = 0; it < 4; ++it) {
        int chunk = tid + 256 * it;
        int row = chunk >> 3, off = (chunk & 7) * 8;
        *(bf16x8*)&obase[(size_t)row * CC + off] = *(bf16x8*)&p_lds[row * 72 + off];
    }
}

// ---------------------------------------------------------------------------
extern "C" void kernel_launch(void* const* d_in, const int* in_sizes, int n_in,
                              void* d_out, int out_size, void* d_ws, size_t ws_size,
                              hipStream_t stream) {
    const float* x = (const float*)d_in[0];
    const float* c = (const float*)d_in[1];
    const float* Wq = (const float*)d_in[3];
    const float* bq = (const float*)d_in[4];
    const float* Wk = (const float*)d_in[5];
    const float* bk = (const float*)d_in[6];
    const float* Wv = (const float*)d_in[7];
    const float* bv = (const float*)d_in[8];
    const float* Wo = (const float*)d_in[9];
    const float* bo = (const float*)d_in[10];

    const size_t MB = 1024ull * 1024ull;
    char* ws = (char*)d_ws;
    __bf16* Wqb  = (__bf16*)(ws + 0 * MB);
    __bf16* Wkb  = (__bf16*)(ws + 2 * MB);
    __bf16* Wvb  = (__bf16*)(ws + 4 * MB);
    __bf16* Wob  = (__bf16*)(ws + 6 * MB);
    __bf16* xT   = (__bf16*)(ws + 8 * MB);
    __bf16* cT   = (__bf16*)(ws + 16 * MB);
    __bf16* qhb  = (__bf16*)(ws + 24 * MB);  // (b,h,t,d) roped+scaled
    __bf16* khb  = (__bf16*)(ws + 32 * MB);  // (b,h,t,d) roped
    __bf16* vbuf = (__bf16*)(ws + 40 * MB);  // (b,C,T)
    __bf16* attT = (__bf16*)(ws + 48 * MB);  // (b,t,c)

    prep_kernel<<<dim3(16, 16, 9), 256, 0, stream>>>(x, c, xT, cT, Wq, Wk, Wv, Wo,
                                                     Wqb, Wkb, Wvb, Wob);
    gemm_qkv_kernel<<<dim3(8, 8, 12), 256, 0, stream>>>(Wqb, Wkb, Wvb, xT, cT, bq, bk, bv,
                                                        qhb, khb, vbuf);
    attn_kernel<<<dim3(64, 8), 256, 0, stream>>>(qhb, khb, vbuf, attT);
    gemm_out_kernel<<<dim3(8, 8, 4), 256, 0, stream>>>(Wob, attT, bo, (float*)d_out);
}

// Round 7
// 204.636 us; speedup vs baseline: 1.0734x; 1.0493x over previous
//
#include <hip/hip_runtime.h>
#include <math.h>

#define BB 4
#define CC 1024
#define TT 1024
#define HH 16
#define HDD 64

typedef float floatx4 __attribute__((ext_vector_type(4)));
typedef __bf16 bf16x8 __attribute__((ext_vector_type(8)));
typedef __bf16 bf16x4 __attribute__((ext_vector_type(4)));

__device__ __forceinline__ void gld_lds16(const __bf16* g, __bf16* l) {
    __builtin_amdgcn_global_load_lds(
        (__attribute__((address_space(1))) void*)(g),
        (__attribute__((address_space(3))) void*)(l), 16, 0, 0);
}

// ---------------------------------------------------------------------------
// Fused prep: z<8 -> transpose (b,C,T) f32 -> (b,T,C) bf16 for x,c;
//             z==8 -> weight f32->bf16 conversion (coalesced).
// ---------------------------------------------------------------------------
__global__ __launch_bounds__(256) void prep_kernel(
    const float* __restrict__ x, const float* __restrict__ c,
    __bf16* __restrict__ xT, __bf16* __restrict__ cT,
    const float* __restrict__ Wq, const float* __restrict__ Wk,
    const float* __restrict__ Wv, const float* __restrict__ Wo,
    __bf16* __restrict__ Wqb, __bf16* __restrict__ Wkb,
    __bf16* __restrict__ Wvb, __bf16* __restrict__ Wob) {
    __shared__ float tile[64][65];
    int tid = threadIdx.x;
    int z = blockIdx.z;
    if (z == 8) {
        const float* srcs[4] = {Wq, Wk, Wv, Wo};
        __bf16* dsts[4] = {Wqb, Wkb, Wvb, Wob};
        int bid = blockIdx.y * 16 + blockIdx.x;   // 0..255
        int mi = bid >> 6;
        const float* s = srcs[mi];
        __bf16* d = dsts[mi];
        int base = (bid & 63) * 16384;
#pragma unroll
        for (int u = 0; u < 16; ++u) {
            int idx = base + u * 1024 + tid * 4;
            float4 v4 = *(const float4*)(s + idx);
            bf16x4 o;
            o[0] = (__bf16)v4.x; o[1] = (__bf16)v4.y;
            o[2] = (__bf16)v4.z; o[3] = (__bf16)v4.w;
            *(bf16x4*)(d + idx) = o;
        }
        return;
    }
    const float* src = (z < 4) ? x : c;
    __bf16* dst = (z < 4) ? xT : cT;
    int b = z & 3;
    int t0 = blockIdx.x * 64, c0 = blockIdx.y * 64;
    int r = tid >> 2, s16 = (tid & 3) * 16;
    const float* sp = src + (size_t)b * CC * TT + (size_t)(c0 + r) * TT + t0 + s16;
    float4 a0 = *(const float4*)(sp + 0);
    float4 a1 = *(const float4*)(sp + 4);
    float4 a2 = *(const float4*)(sp + 8);
    float4 a3 = *(const float4*)(sp + 12);
    float* tr = &tile[r][s16];
    tr[0] = a0.x; tr[1] = a0.y; tr[2]  = a0.z; tr[3]  = a0.w;
    tr[4] = a1.x; tr[5] = a1.y; tr[6]  = a1.z; tr[7]  = a1.w;
    tr[8] = a2.x; tr[9] = a2.y; tr[10] = a2.z; tr[11] = a2.w;
    tr[12] = a3.x; tr[13] = a3.y; tr[14] = a3.z; tr[15] = a3.w;
    __syncthreads();
    bf16x8 p0, p1;
#pragma unroll
    for (int j = 0; j < 8; ++j) {
        p0[j] = (__bf16)tile[s16 + j][r];
        p1[j] = (__bf16)tile[s16 + 8 + j][r];
    }
    __bf16* dp = dst + (size_t)b * TT * CC + (size_t)(t0 + r) * CC + c0 + s16;
    *(bf16x8*)(dp) = p0;
    *(bf16x8*)(dp + 8) = p1;
}

// ---------------------------------------------------------------------------
// 128x128 tile, BK=32 DOUBLE-BUFFERED bf16 MFMA GEMM, B^T input.
// Ping-pong: barrier -> stage(kt+1) -> compute(kt): every staged load has a
// full compute phase in flight before the barrier that drains it.
// smem: A0@0, B0@4096, A1@8192, B1@12288 (elems, [128][32] each, 8 KB);
// epilogue reuses smem as [256][72] (18432 elems = 36 KB alloc).
// Fragment layout: row stride 32 elems; col-group v = lq ^ (lm&3) -> bank
// start (lm&1)*16 + v*4: 8 lanes/bank-quad = uniform = conflict-free b128.
// EPI 0: out bf16 (b,C,T) + bias | EPI 1: rope -> (h,t,d) | EPI 2: f32 + bias
// ---------------------------------------------------------------------------
template <int EPI, typename OutT>
__device__ __forceinline__ void gemm_bt32(
    __bf16* smem, const __bf16* __restrict__ A, const __bf16* __restrict__ Bt,
    const float* __restrict__ bias, OutT* __restrict__ out, float qs) {
    const int tid = threadIdx.x, l = tid & 63, w = tid >> 6;
    const int m0 = blockIdx.y * 128, n0 = blockIdx.x * 128;
    const int wm = (w >> 1) * 64, wn = (w & 1) * 64;
    const int lm = l & 15, lq = l >> 4;
    const int v8 = (lq ^ (lm & 3)) * 8;          // swizzled col-group (read)
    const int srow = l >> 2;                     // 0..15 staging row
    const int gcg = ((l & 3) ^ ((l >> 2) & 3)) * 8;  // global-side swizzle

    // wave w stages rows w*32..w*32+31 of A and B (2 chunks of 16 rows each)
    const __bf16* ga = A + (size_t)(m0 + w * 32 + srow) * 1024 + gcg;
    const __bf16* gb = Bt + (size_t)(n0 + w * 32 + srow) * 1024 + gcg;
    __bf16* adst = smem + w * 1024;          // + buffer offset
    __bf16* bdst = smem + 4096 + w * 1024;

#define GSTAGE(BUFOFF)                                       \
    do {                                                     \
        gld_lds16(ga, adst + (BUFOFF));                      \
        gld_lds16(ga + 16 * 1024, adst + (BUFOFF) + 512);    \
        gld_lds16(gb, bdst + (BUFOFF));                      \
        gld_lds16(gb + 16 * 1024, bdst + (BUFOFF) + 512);    \
        ga += 32;                                            \
        gb += 32;                                            \
    } while (0)

#define GCOMP(BUFOFF)                                                          \
    do {                                                                       \
        bf16x8 af[4], bfr[4];                                                  \
        _Pragma("unroll") for (int i = 0; i < 4; ++i)                          \
            af[i] = *(bf16x8*)&smem[(BUFOFF) + (wm + i * 16 + lm) * 32 + v8];  \
        _Pragma("unroll") for (int j = 0; j < 4; ++j)                          \
            bfr[j] = *(bf16x8*)&smem[(BUFOFF) + 4096 + (wn + j * 16 + lm) * 32 + v8]; \
        _Pragma("unroll") for (int i = 0; i < 4; ++i)                          \
            _Pragma("unroll") for (int j = 0; j < 4; ++j)                      \
                acc[i][j] = __builtin_amdgcn_mfma_f32_16x16x32_bf16(af[i], bfr[j], acc[i][j], 0, 0, 0); \
    } while (0)

    floatx4 acc[4][4];
#pragma unroll
    for (int i = 0; i < 4; ++i)
#pragma unroll
        for (int j = 0; j < 4; ++j) acc[i][j] = (floatx4){0.f, 0.f, 0.f, 0.f};

    GSTAGE(0);  // kt 0
#pragma unroll 1
    for (int kt = 0; kt < 32; kt += 2) {
        __syncthreads();        // buf0(kt) ready; prior buf1 reads done
        GSTAGE(8192);           // stage kt+1 (in flight across compute)
        GCOMP(0);               // compute kt
        __syncthreads();        // buf1(kt+1) ready; buf0 reads done
        if (kt + 2 < 32) GSTAGE(0);  // stage kt+2
        GCOMP(8192);            // compute kt+1
    }
#undef GSTAGE
#undef GCOMP

    if (EPI == 1) {
        // ---- bias + RoPE in registers, write (h,t,d) via LDS bounce ----
        float b4[4][4];
#pragma unroll
        for (int i = 0; i < 4; ++i)
#pragma unroll
            for (int r = 0; r < 4; ++r) b4[i][r] = bias[m0 + wm + i * 16 + lq * 4 + r];
#pragma unroll
        for (int r = 0; r < 4; ++r) {
            // theta = 10000^(-(lq*4+r)/16)
            float theta = __expf(-0.57564627f * (float)(lq * 4 + r));
#pragma unroll
            for (int j = 0; j < 4; ++j) {
                float ang = (float)(n0 + wn + j * 16 + lm) * theta;
                float cs = __cosf(ang), sn = __sinf(ang);
                float a0 = acc[0][j][r] + b4[0][r];
                float a1 = acc[1][j][r] + b4[1][r];
                acc[0][j][r] = (a0 * cs - a1 * sn) * qs;
                acc[1][j][r] = (a1 * cs + a0 * sn) * qs;
                acc[2][j][r] = (acc[2][j][r] + b4[2][r]) * qs;
                acc[3][j][r] = (acc[3][j][r] + b4[3][r]) * qs;
            }
        }
        __syncthreads();  // all frag reads done; reuse smem as o_lds [256][72]
        const int hl = wm >> 6;
#pragma unroll
        for (int j = 0; j < 4; ++j) {
            int row = hl * 128 + wn + j * 16 + lm;
#pragma unroll
            for (int i = 0; i < 4; ++i) {
                bf16x4 pk;
#pragma unroll
                for (int r = 0; r < 4; ++r) pk[r] = (__bf16)acc[i][j][r];
                *(bf16x4*)&smem[row * 72 + i * 16 + lq * 4] = pk;
            }
        }
        __syncthreads();
        const size_t hbase = (size_t)(m0 >> 6) * (TT * 64);
#pragma unroll
        for (int it = 0; it < 8; ++it) {
            int chunk = tid + 256 * it;
            int row = chunk >> 3, off = (chunk & 7) * 8;  // row 0..255
            int hh = row >> 7, t = n0 + (row & 127);
            *(bf16x8*)&out[hbase + (size_t)hh * (TT * 64) + (size_t)t * 64 + off] =
                *(bf16x8*)&smem[row * 72 + off];
        }
    } else {
#pragma unroll
        for (int i = 0; i < 4; ++i) {
            int mbase = m0 + wm + i * 16 + lq * 4;
#pragma unroll
            for (int r = 0; r < 4; ++r) {
                float bv = bias[mbase + r];
                size_t rowoff = (size_t)(mbase + r) * 1024 + n0 + wn + lm;
#pragma unroll
                for (int j = 0; j < 4; ++j)
                    out[rowoff + j * 16] = (OutT)(acc[i][j][r] + bv);
            }
        }
    }
}

__global__ __launch_bounds__(256) void gemm_qkv_kernel(
    const __bf16* __restrict__ Wqb, const __bf16* __restrict__ Wkb, const __bf16* __restrict__ Wvb,
    const __bf16* __restrict__ xT, const __bf16* __restrict__ cT,
    const float* __restrict__ bq, const float* __restrict__ bk, const float* __restrict__ bv,
    __bf16* __restrict__ qhb, __bf16* __restrict__ khb, __bf16* __restrict__ vb) {
    __shared__ __bf16 smem[18432];  // single 36 KB allocation for all EPI paths
    int z = blockIdx.z, which = z >> 2, b = z & 3;
    if (which == 0) {
        gemm_bt32<1, __bf16>(smem, Wqb, xT + (size_t)b * TT * CC, bq,
                             qhb + (size_t)b * HH * TT * 64, 0.18033688f);
    } else if (which == 1) {
        gemm_bt32<1, __bf16>(smem, Wkb, cT + (size_t)b * TT * CC, bk,
                             khb + (size_t)b * HH * TT * 64, 1.0f);
    } else {
        gemm_bt32<0, __bf16>(smem, Wvb, cT + (size_t)b * TT * CC, bv,
                             vb + (size_t)b * CC * TT, 1.0f);
    }
}

__global__ __launch_bounds__(256) void gemm_out_kernel(
    const __bf16* __restrict__ Wob, const __bf16* __restrict__ attT,
    const float* __restrict__ bo, float* __restrict__ out) {
    __shared__ __bf16 smem[18432];
    int b = blockIdx.z;
    gemm_bt32<2, float>(smem, Wob, attT + (size_t)b * TT * CC, bo,
                        out + (size_t)b * CC * TT, 1.0f);
}

// ---------------------------------------------------------------------------
// Flash-style attention (v4 structure):
//  - 32 q-rows/wave, Q fragments in registers, double-buffered K/V,
//    one barrier per tile, stage-ahead.
// ---------------------------------------------------------------------------
#define ATTN_STAGE(KB, VB)                      \
    do {                                        \
        gld_lds16(kg, &KB[w * 1024]);           \
        gld_lds16(kg + 512, &KB[w * 1024 + 512]); \
        gld_lds16(vg, &VB[w * 1024]);           \
        gld_lds16(vg + 8 * TT, &VB[w * 1024 + 512]); \
        kg += 4096;                             \
        vg += 64;                               \
    } while (0)

#define ATTN_STEP(KB, VB)                                                            \
    do {                                                                             \
        floatx4 sT[2][4];                                                            \
        _Pragma("unroll") for (int i = 0; i < 4; ++i) {                              \
            sT[0][i] = (floatx4){0.f, 0.f, 0.f, 0.f};                                \
            sT[1][i] = (floatx4){0.f, 0.f, 0.f, 0.f};                                \
        }                                                                            \
        _Pragma("unroll") for (int i = 0; i < 4; ++i) {                              \
            bf16x8 kf0 = *(bf16x8*)&KB[koff + i * 1024 + cg0];                       \
            bf16x8 kf1 = *(bf16x8*)&KB[koff + i * 1024 + cg1];                       \
            sT[0][i] = __builtin_amdgcn_mfma_f32_16x16x32_bf16(kf0, qf00, sT[0][i], 0, 0, 0); \
            sT[0][i] = __builtin_amdgcn_mfma_f32_16x16x32_bf16(kf1, qf01, sT[0][i], 0, 0, 0); \
            sT[1][i] = __builtin_amdgcn_mfma_f32_16x16x32_bf16(kf0, qf10, sT[1][i], 0, 0, 0); \
            sT[1][i] = __builtin_amdgcn_mfma_f32_16x16x32_bf16(kf1, qf11, sT[1][i], 0, 0, 0); \
        }                                                                            \
        float rs0 = 0.f, rs1 = 0.f;                                                  \
        _Pragma("unroll") for (int i = 0; i < 4; ++i)                                \
            _Pragma("unroll") for (int r = 0; r < 4; ++r) {                          \
                float e0 = __builtin_amdgcn_exp2f(sT[0][i][r]);                      \
                float e1 = __builtin_amdgcn_exp2f(sT[1][i][r]);                      \
                sT[0][i][r] = e0; rs0 += e0;                                         \
                sT[1][i][r] = e1; rs1 += e1;                                         \
            }                                                                        \
        rs0 += __shfl_xor(rs0, 16, 64); rs0 += __shfl_xor(rs0, 32, 64);              \
        rs1 += __shfl_xor(rs1, 16, 64); rs1 += __shfl_xor(rs1, 32, 64);              \
        l_acc0 += rs0; l_acc1 += rs1;                                                \
        _Pragma("unroll") for (int i = 0; i < 4; ++i) {                              \
            bf16x4 p0, p1;                                                           \
            _Pragma("unroll") for (int r = 0; r < 4; ++r) {                          \
                p0[r] = (__bf16)sT[0][i][r];                                         \
                p1[r] = (__bf16)sT[1][i][r];                                         \
            }                                                                        \
            *(bf16x4*)&pwl[i * 16 + lq * 4] = p0;                                    \
            *(bf16x4*)&pwl[1152 + i * 16 + lq * 4] = p1;                             \
        }                                                                            \
        asm volatile("s_waitcnt lgkmcnt(0)" ::: "memory");                           \
        _Pragma("unroll") for (int ss = 0; ss < 2; ++ss) {                           \
            bf16x8 ap0 = *(bf16x8*)&pwl[ss * 32 + lq * 8];                           \
            bf16x8 ap1 = *(bf16x8*)&pwl[1152 + ss * 32 + lq * 8];                    \
            const int cgv = ss ? cg1 : cg0;                                          \
            _Pragma("unroll") for (int j = 0; j < 4; ++j) {                          \
                bf16x8 vf = *(bf16x8*)&VB[koff + j * 1024 + cgv];                    \
                o_acc[0][j] = __builtin_amdgcn_mfma_f32_16x16x32_bf16(ap0, vf, o_acc[0][j], 0, 0, 0); \
                o_acc[1][j] = __builtin_amdgcn_mfma_f32_16x16x32_bf16(ap1, vf, o_acc[1][j], 0, 0, 0); \
            }                                                                        \
        }                                                                            \
    } while (0)

__global__ __launch_bounds__(256, 4) void attn_kernel(
    const __bf16* __restrict__ qh, const __bf16* __restrict__ kh,
    const __bf16* __restrict__ v, __bf16* __restrict__ attT) {
    const int bh = blockIdx.x, b = bh >> 4, h = bh & 15;
    const int tq0 = blockIdx.y * 128;
    const int tid = threadIdx.x, l = tid & 63, w = tid >> 6;
    const int lm = l & 15, lq = l >> 4;

    __shared__ __bf16 k0[4096], v0[4096], k1[4096], v1[4096];
    __shared__ __bf16 p_lds[9216];  // 4 waves x [32 t][72]

    const int cg0 = (lq ^ (lm & 7)) * 8;
    const int cg1 = ((4 + lq) ^ (lm & 7)) * 8;
    const int koff = lm * 64;
    __bf16* pwl = p_lds + w * 2304 + lm * 72;

    const __bf16* qbase = qh + (size_t)bh * TT * 64 + (size_t)(tq0 + w * 32 + lm) * 64 + lq * 8;
    bf16x8 qf00 = *(const bf16x8*)(qbase);
    bf16x8 qf01 = *(const bf16x8*)(qbase + 32);
    bf16x8 qf10 = *(const bf16x8*)(qbase + 1024);
    bf16x8 qf11 = *(const bf16x8*)(qbase + 1024 + 32);

    const int srow = l >> 3, scg = l & 7;
    const int gcg = (scg ^ srow) * 8;
    const __bf16* kg = kh + (size_t)bh * TT * 64 + (size_t)(w * 16 + srow) * 64 + gcg;
    const __bf16* vg = v + (size_t)b * CC * TT + (size_t)(h * 64 + w * 16 + srow) * TT + gcg;

    floatx4 o_acc[2][4];
#pragma unroll
    for (int j = 0; j < 4; ++j) {
        o_acc[0][j] = (floatx4){0.f, 0.f, 0.f, 0.f};
        o_acc[1][j] = (floatx4){0.f, 0.f, 0.f, 0.f};
    }
    float l_acc0 = 0.f, l_acc1 = 0.f;

    ATTN_STAGE(k0, v0);
#pragma unroll 1
    for (int st = 0; st < 16; st += 2) {
        __syncthreads();
        ATTN_STAGE(k1, v1);
        ATTN_STEP(k0, v0);
        __syncthreads();
        if (st + 2 < 16) ATTN_STAGE(k0, v0);
        ATTN_STEP(k1, v1);
    }

    float inv0[4], inv1[4];
#pragma unroll
    for (int r = 0; r < 4; ++r) {
        inv0[r] = 1.0f / __shfl(l_acc0, lq * 4 + r, 64);
        inv1[r] = 1.0f / __shfl(l_acc1, lq * 4 + r, 64);
    }
#pragma unroll
    for (int j = 0; j < 4; ++j)
#pragma unroll
        for (int r = 0; r < 4; ++r) {
            p_lds[(w * 32 + lq * 4 + r) * 72 + j * 16 + lm] = (__bf16)(o_acc[0][j][r] * inv0[r]);
            p_lds[(w * 32 + 16 + lq * 4 + r) * 72 + j * 16 + lm] = (__bf16)(o_acc[1][j][r] * inv1[r]);
        }
    __syncthreads();
    __bf16* obase = attT + (size_t)b * TT * CC + (size_t)tq0 * CC + h * 64;
#pragma unroll
    for (int it = 0; it < 4; ++it) {
        int chunk = tid + 256 * it;
        int row = chunk >> 3, off = (chunk & 7) * 8;
        *(bf16x8*)&obase[(size_t)row * CC + off] = *(bf16x8*)&p_lds[row * 72 + off];
    }
}

// ---------------------------------------------------------------------------
extern "C" void kernel_launch(void* const* d_in, const int* in_sizes, int n_in,
                              void* d_out, int out_size, void* d_ws, size_t ws_size,
                              hipStream_t stream) {
    const float* x = (const float*)d_in[0];
    const float* c = (const float*)d_in[1];
    const float* Wq = (const float*)d_in[3];
    const float* bq = (const float*)d_in[4];
    const float* Wk = (const float*)d_in[5];
    const float* bk = (const float*)d_in[6];
    const float* Wv = (const float*)d_in[7];
    const float* bv = (const float*)d_in[8];
    const float* Wo = (const float*)d_in[9];
    const float* bo = (const float*)d_in[10];

    const size_t MB = 1024ull * 1024ull;
    char* ws = (char*)d_ws;
    __bf16* Wqb  = (__bf16*)(ws + 0 * MB);
    __bf16* Wkb  = (__bf16*)(ws + 2 * MB);
    __bf16* Wvb  = (__bf16*)(ws + 4 * MB);
    __bf16* Wob  = (__bf16*)(ws + 6 * MB);
    __bf16* xT   = (__bf16*)(ws + 8 * MB);
    __bf16* cT   = (__bf16*)(ws + 16 * MB);
    __bf16* qhb  = (__bf16*)(ws + 24 * MB);  // (b,h,t,d) roped+scaled
    __bf16* khb  = (__bf16*)(ws + 32 * MB);  // (b,h,t,d) roped
    __bf16* vbuf = (__bf16*)(ws + 40 * MB);  // (b,C,T)
    __bf16* attT = (__bf16*)(ws + 48 * MB);  // (b,t,c)

    prep_kernel<<<dim3(16, 16, 9), 256, 0, stream>>>(x, c, xT, cT, Wq, Wk, Wv, Wo,
                                                     Wqb, Wkb, Wvb, Wob);
    gemm_qkv_kernel<<<dim3(8, 8, 12), 256, 0, stream>>>(Wqb, Wkb, Wvb, xT, cT, bq, bk, bv,
                                                        qhb, khb, vbuf);
    attn_kernel<<<dim3(64, 8), 256, 0, stream>>>(qhb, khb, vbuf, attT);
    gemm_out_kernel<<<dim3(8, 8, 4), 256, 0, stream>>>(Wob, attT, bo, (float*)d_out);
}